// Round 8
// baseline (314.715 us; speedup 1.0000x reference)
//
#include <hip/hip_runtime.h>
#include <hip/hip_bf16.h>

typedef unsigned short u16;
typedef unsigned int   u32;
typedef __attribute__((ext_vector_type(8))) short bf16x8;
typedef __attribute__((ext_vector_type(4))) float f32x4;
typedef __attribute__((ext_vector_type(4))) float f4v;
typedef __attribute__((ext_vector_type(4))) u16  u16x4;

#define BB 2
#define SS 2048
#define DD 1024
#define HH 16
#define NT 4096          // B*S tokens
#define ATT_SCALE 0.125f // 1/sqrt(64)

__device__ __forceinline__ u16 f2bf(float f) {
  union { float f; u32 u; } c; c.f = f;
  u32 u = c.u + 0x7fffu + ((c.u >> 16) & 1u);
  return (u16)(u >> 16);
}

__device__ __forceinline__ void gload_lds16(const void* g, void* l) {
  __builtin_amdgcn_global_load_lds(
      (const __attribute__((address_space(1))) u32*)g,
      (__attribute__((address_space(3))) u32*)l, 16, 0, 0);
}

// ---------------------------------------------------------------- conversion
__global__ void cvt_bf16_kernel(const float* __restrict__ s0, const float* __restrict__ s1,
                                const float* __restrict__ s2, const float* __restrict__ s3,
                                u16* __restrict__ d0, u16* __restrict__ d1,
                                u16* __restrict__ d2, u16* __restrict__ d3, int n4) {
  const int z = blockIdx.y;
  const float* s = (z == 0) ? s0 : (z == 1) ? s1 : (z == 2) ? s2 : s3;
  u16* d = (z == 0) ? d0 : (z == 1) ? d1 : (z == 2) ? d2 : d3;
  int i = blockIdx.x * blockDim.x + threadIdx.x;
  int stride = gridDim.x * blockDim.x;
  for (int k = i; k < n4; k += stride) {
    f4v v = ((const f4v*)s)[k];
    u16x4 o;
    o[0] = f2bf(v[0]); o[1] = f2bf(v[1]); o[2] = f2bf(v[2]); o[3] = f2bf(v[3]);
    ((u16x4*)d)[k] = o;
  }
}

// ---------------------------------------------------------------- GEMM  C = A * W^T (+bias)
// m97 structure: 128x128 tile, BK=64, 4 waves (2x2), single-buffer LDS (32KB),
// 2 barriers/K-step, global_load_lds width-16, XOR-swizzled frag reads (2-way=free).
template<int OUT_F32, int BIAS_ROW>
__global__ __launch_bounds__(256, 2) void gemm_bt_kernel(
    const u16* __restrict__ A0, const u16* __restrict__ A1, const u16* __restrict__ A2,
    const u16* __restrict__ W0, const u16* __restrict__ W1, const u16* __restrict__ W2,
    const float* __restrict__ b0, const float* __restrict__ b1, const float* __restrict__ b2,
    void* __restrict__ C0, void* __restrict__ C1, void* __restrict__ C2,
    int M, int N, int K) {
  const int z = blockIdx.z;
  const u16* A = (z == 0) ? A0 : (z == 1) ? A1 : A2;
  const u16* W = (z == 0) ? W0 : (z == 1) ? W1 : W2;
  const float* bias = (z == 0) ? b0 : (z == 1) ? b1 : b2;
  void* Cp = (z == 0) ? C0 : (z == 1) ? C1 : C2;

  __shared__ u16 As[128 * 64];
  __shared__ u16 Bs[128 * 64];
  const int t = threadIdx.x;
  const int lane = t & 63, w = t >> 6;
  const int wr = w >> 1, wc = w & 1;
  const int l15 = lane & 15, l4 = lane >> 4;
  const int m0 = blockIdx.x * 128, n0 = blockIdx.y * 128;

  f32x4 acc[4][4];
#pragma unroll
  for (int m = 0; m < 4; ++m)
#pragma unroll
    for (int n = 0; n < 4; ++n) acc[m][n] = (f32x4)(0.0f);

  // pre-swizzled global sources (rule 21): LDS granule c holds global granule (c&7)^(row&7)
  const u16* aSrc[4];
  const u16* bSrc[4];
#pragma unroll
  for (int i = 0; i < 4; ++i) {
    int c = i * 256 + t, row = c >> 3, gg = (c & 7) ^ (row & 7);
    aSrc[i] = A + (size_t)(m0 + row) * K + gg * 8;
    bSrc[i] = W + (size_t)(n0 + row) * K + gg * 8;
  }

  const int nk = K >> 6;
  for (int kt = 0; kt < nk; ++kt) {
    __syncthreads();
#pragma unroll
    for (int i = 0; i < 4; ++i) {
      gload_lds16(aSrc[i] + kt * 64, &As[i * 2048 + w * 512]);
      gload_lds16(bSrc[i] + kt * 64, &Bs[i * 2048 + w * 512]);
    }
    __syncthreads();
    bf16x8 af[4][2], bfr[4][2];
#pragma unroll
    for (int m = 0; m < 4; ++m) {
      int row = wr * 64 + m * 16 + l15;
#pragma unroll
      for (int kf = 0; kf < 2; ++kf)
        af[m][kf] = *(const bf16x8*)&As[row * 64 + ((kf * 4 + l4) ^ (row & 7)) * 8];
    }
#pragma unroll
    for (int n = 0; n < 4; ++n) {
      int row = wc * 64 + n * 16 + l15;
#pragma unroll
      for (int kf = 0; kf < 2; ++kf)
        bfr[n][kf] = *(const bf16x8*)&Bs[row * 64 + ((kf * 4 + l4) ^ (row & 7)) * 8];
    }
#pragma unroll
    for (int kf = 0; kf < 2; ++kf)
#pragma unroll
      for (int m = 0; m < 4; ++m)
#pragma unroll
        for (int n = 0; n < 4; ++n)
          acc[m][n] = __builtin_amdgcn_mfma_f32_16x16x32_bf16(af[m][kf], bfr[n][kf], acc[m][n], 0, 0, 0);
  }

  float bvc[4];
#pragma unroll
  for (int n = 0; n < 4; ++n)
    bvc[n] = BIAS_ROW ? 0.0f : bias[n0 + wc * 64 + n * 16 + l15];
#pragma unroll
  for (int m = 0; m < 4; ++m) {
#pragma unroll
    for (int j = 0; j < 4; ++j) {
      int r = m0 + wr * 64 + m * 16 + l4 * 4 + j;
      float br = BIAS_ROW ? bias[r] : 0.0f;
#pragma unroll
      for (int n = 0; n < 4; ++n) {
        int cc = n0 + wc * 64 + n * 16 + l15;
        float v = acc[m][n][j] + (BIAS_ROW ? br : bvc[n]);
        if (OUT_F32) ((float*)Cp)[(size_t)r * N + cc] = v;
        else         ((u16*)Cp)[(size_t)r * N + cc] = f2bf(v);
      }
    }
  }
}

// ---------------------------------------------------------------- causal flash attention
// One wave per block, QBLK=16 rows, KBLK=64, zero barriers. Triangle pairing:
// block p handles q-strips {p, 127-p} -> exactly 33 k-tiles per block (perfect
// balance). Register ping-pong K-prefetch; V direct from pre-transposed VtT.
// Row-sums via ones-column MFMA (no sum shfl chain); T13 defer-max (THR=8).
__global__ __launch_bounds__(64, 2) void attn_kernel(
    const u16* __restrict__ Qb, const u16* __restrict__ Kb,
    const u16* __restrict__ VtT, u16* __restrict__ Xb) {
  __shared__ u16 Pl[16 * 72];

  const int p = blockIdx.x;            // pair id 0..63
  const int bh = blockIdx.y;
  const int b = bh >> 4, h = bh & 15;
  const int lane = threadIdx.x & 63;
  const int l15 = lane & 15, l4 = lane >> 4;

  const u16* Kbase = Kb + (size_t)b * SS * DD + h * 64;
  const u16* Vbase = VtT + (size_t)h * 64 * NT + (size_t)b * SS;

  // ones B-fragment: output col 0 = sum over k of P[row][k]
  bf16x8 onesf;
#pragma unroll
  for (int e = 0; e < 8; ++e) onesf[e] = (l15 == 0) ? (short)0x3F80 : (short)0;

  for (int si = 0; si < 2; ++si) {
    const int qt = si ? (127 - p) : p;
    const int q0 = qt * 16;

    bf16x8 aq[2];
#pragma unroll
    for (int kf = 0; kf < 2; ++kf)
      aq[kf] = *(const bf16x8*)&Qb[((size_t)b * SS + q0 + l15) * DD + h * 64 + kf * 32 + l4 * 8];

    f32x4 acc[4], accsum;
    float mrun[4];
#pragma unroll
    for (int x = 0; x < 4; ++x) { acc[x] = (f32x4)(0.0f); mrun[x] = -3.0e38f; }
    accsum = (f32x4)(0.0f);

    auto loadK = [&](int kt, bf16x8 kfr[4][2]) {
      const int k0 = kt * 64;
#pragma unroll
      for (int nf = 0; nf < 4; ++nf) {
        const u16* kr = Kbase + (size_t)(k0 + nf * 16 + l15) * DD + l4 * 8;
        kfr[nf][0] = *(const bf16x8*)kr;
        kfr[nf][1] = *(const bf16x8*)(kr + 32);
      }
    };

    auto compute = [&](int kt, bf16x8 kfr[4][2]) {
      const int k0 = kt * 64;
      f32x4 s[4];
#pragma unroll
      for (int nf = 0; nf < 4; ++nf) s[nf] = (f32x4)(0.0f);

      __builtin_amdgcn_s_setprio(1);
#pragma unroll
      for (int nf = 0; nf < 4; ++nf)
#pragma unroll
        for (int kf = 0; kf < 2; ++kf)
          s[nf] = __builtin_amdgcn_mfma_f32_16x16x32_bf16(aq[kf], kfr[nf][kf], s[nf], 0, 0, 0);
      __builtin_amdgcn_s_setprio(0);

      // V fragments issued now — softmax below covers the latency
      bf16x8 vf[4][2];
#pragma unroll
      for (int nd = 0; nd < 4; ++nd) {
        const u16* vr = Vbase + (size_t)(nd * 16 + l15) * NT + k0 + l4 * 8;
        vf[nd][0] = *(const bf16x8*)vr;
        vf[nd][1] = *(const bf16x8*)(vr + 32);
      }

      const bool need_mask = (k0 + 63 > q0);
#pragma unroll
      for (int nf = 0; nf < 4; ++nf)
#pragma unroll
        for (int j = 0; j < 4; ++j) {
          float v = s[nf][j] * ATT_SCALE;
          if (need_mask) {
            int key = k0 + nf * 16 + l15;
            int qrow = q0 + l4 * 4 + j;
            if (key > qrow) v = -1.0e9f;
          }
          s[nf][j] = v;
        }

      // row max (4-shfl chain per row); sum handled by ones-MFMA
      float pmax[4];
#pragma unroll
      for (int j = 0; j < 4; ++j) {
        float v = fmaxf(fmaxf(s[0][j], s[1][j]), fmaxf(s[2][j], s[3][j]));
        v = fmaxf(v, __shfl_xor(v, 1));
        v = fmaxf(v, __shfl_xor(v, 2));
        v = fmaxf(v, __shfl_xor(v, 4));
        v = fmaxf(v, __shfl_xor(v, 8));
        pmax[j] = v;
      }

      // T13 defer-max: rescale only when max grew by > 8
      int ok = 1;
#pragma unroll
      for (int j = 0; j < 4; ++j) ok &= (pmax[j] - mrun[j] <= 8.0f) ? 1 : 0;
      if (!__all(ok)) {
#pragma unroll
        for (int j = 0; j < 4; ++j) {
          float mnew = fmaxf(mrun[j], pmax[j]);
          float sc = __expf(mrun[j] - mnew);
          mrun[j] = mnew;
          accsum[j] *= sc;
#pragma unroll
          for (int nd = 0; nd < 4; ++nd) acc[nd][j] *= sc;
        }
      }

#pragma unroll
      for (int nf = 0; nf < 4; ++nf)
#pragma unroll
        for (int j = 0; j < 4; ++j)
          s[nf][j] = __expf(s[nf][j] - mrun[j]);

      // P relayout through wave-local LDS (no barriers)
#pragma unroll
      for (int nf = 0; nf < 4; ++nf)
#pragma unroll
        for (int j = 0; j < 4; ++j)
          Pl[(l4 * 4 + j) * 72 + nf * 16 + l15] = f2bf(s[nf][j]);

      bf16x8 ap[2];
#pragma unroll
      for (int kf = 0; kf < 2; ++kf)
        ap[kf] = *(const bf16x8*)&Pl[l15 * 72 + kf * 32 + l4 * 8];

      __builtin_amdgcn_s_setprio(1);
#pragma unroll
      for (int nd = 0; nd < 4; ++nd)
#pragma unroll
        for (int kf = 0; kf < 2; ++kf)
          acc[nd] = __builtin_amdgcn_mfma_f32_16x16x32_bf16(ap[kf], vf[nd][kf], acc[nd], 0, 0, 0);
#pragma unroll
      for (int kf = 0; kf < 2; ++kf)
        accsum = __builtin_amdgcn_mfma_f32_16x16x32_bf16(ap[kf], onesf, accsum, 0, 0, 0);
      __builtin_amdgcn_s_setprio(0);
    };

    const int nkt = (qt >> 2) + 1;
    bf16x8 kA[4][2], kB[4][2];
    loadK(0, kA);
    for (int kt = 0; kt < nkt;) {
      if (kt + 1 < nkt) loadK(kt + 1, kB);  // prefetch off the critical path
      compute(kt, kA);
      ++kt;
      if (kt >= nkt) break;
      if (kt + 1 < nkt) loadK(kt + 1, kA);
      compute(kt, kB);
      ++kt;
    }

    // epilogue: lsum lives in l15==0 lanes of accsum; broadcast then write
#pragma unroll
    for (int j = 0; j < 4; ++j) {
      float lsum = __shfl(accsum[j], l4 * 16);
      float inv = 1.0f / lsum;
      int srow = q0 + l4 * 4 + j;
      size_t base = (size_t)b * SS * DD + (size_t)h * SS * 64 + (size_t)srow * 64;
#pragma unroll
      for (int nd = 0; nd < 4; ++nd)
        Xb[base + nd * 16 + l15] = f2bf(acc[nd][j] * inv);
    }
  }
}

// ---------------------------------------------------------------- launch
extern "C" void kernel_launch(void* const* d_in, const int* in_sizes, int n_in,
                              void* d_out, int out_size, void* d_ws, size_t ws_size,
                              hipStream_t stream) {
  const float* q_in = (const float*)d_in[0];
  const float* k_in = (const float*)d_in[1];
  const float* v_in = (const float*)d_in[2];
  const float* Wq = (const float*)d_in[3];
  const float* bq = (const float*)d_in[4];
  const float* Wk = (const float*)d_in[5];
  const float* bk = (const float*)d_in[6];
  const float* Wv = (const float*)d_in[7];
  const float* bv = (const float*)d_in[8];
  const float* Wo = (const float*)d_in[9];
  const float* bo = (const float*)d_in[10];

  char* ws = (char*)d_ws;
  const size_t SZ_IN = (size_t)BB * SS * DD * 2;  // 8 MiB bf16
  const size_t SZ_W = (size_t)DD * DD * 2;        // 2 MiB bf16
  u16* qb  = (u16*)(ws);
  u16* kb  = (u16*)(ws + SZ_IN);
  u16* vb  = (u16*)(ws + 2 * SZ_IN);
  u16* wqb = (u16*)(ws + 3 * SZ_IN);
  u16* wkb = (u16*)(ws + 3 * SZ_IN + SZ_W);
  u16* wvb = (u16*)(ws + 3 * SZ_IN + 2 * SZ_W);
  u16* wob = (u16*)(ws + 3 * SZ_IN + 3 * SZ_W);
  u16* Qb  = (u16*)(ws + 3 * SZ_IN + 4 * SZ_W);
  u16* Kb  = (u16*)(ws + 4 * SZ_IN + 4 * SZ_W);
  u16* VtT = (u16*)(ws + 5 * SZ_IN + 4 * SZ_W);  // [1024 dims][4096 tokens]
  u16* Xb  = (u16*)(ws + 6 * SZ_IN + 4 * SZ_W);

  // fp32 -> bf16
  cvt_bf16_kernel<<<dim3(2048, 3), 256, 0, stream>>>(q_in, k_in, v_in, nullptr,
                                                     qb, kb, vb, nullptr, (BB * SS * DD) / 4);
  cvt_bf16_kernel<<<dim3(1024, 4), 256, 0, stream>>>(Wq, Wk, Wv, Wo,
                                                     wqb, wkb, wvb, wob, (DD * DD) / 4);

  // Q & K & V projections... Q/K = X @ W^T + b -> [4096][1024] (z=0,1)
  gemm_bt_kernel<0, 0><<<dim3(32, 8, 2), 256, 0, stream>>>(
      qb, kb, nullptr, wqb, wkb, nullptr, bq, bk, nullptr, Qb, Kb, nullptr, NT, DD, DD);

  // V projection, transposed output:  V^T = Wv @ X^T (+bias by row) -> [1024][4096]
  gemm_bt_kernel<0, 1><<<dim3(8, 32, 1), 256, 0, stream>>>(
      wvb, nullptr, nullptr, vb, nullptr, nullptr, bv, nullptr, nullptr,
      VtT, nullptr, nullptr, DD, NT, DD);

  // causal attention (balanced pairs, barrier-free)
  attn_kernel<<<dim3(64, BB * HH), 64, 0, stream>>>(Qb, Kb, VtT, Xb);

  // output projection (fp32 out)
  gemm_bt_kernel<1, 0><<<dim3(32, 8, 1), 256, 0, stream>>>(
      Xb, nullptr, nullptr, wob, nullptr, nullptr, bo, nullptr, nullptr,
      d_out, nullptr, nullptr, NT, DD, DD);
}

// Round 9
// 303.175 us; speedup vs baseline: 1.0381x; 1.0381x over previous
//
#include <hip/hip_runtime.h>
#include <hip/hip_bf16.h>

typedef unsigned short u16;
typedef unsigned int   u32;
typedef __attribute__((ext_vector_type(8))) short bf16x8;
typedef __attribute__((ext_vector_type(4))) float f32x4;
typedef __attribute__((ext_vector_type(4))) float f4v;
typedef __attribute__((ext_vector_type(4))) u16  u16x4;

#define BB 2
#define SS 2048
#define DD 1024
#define HH 16
#define NT 4096          // B*S tokens
#define ATT_SCALE 0.125f // 1/sqrt(64)

__device__ __forceinline__ u16 f2bf(float f) {
  union { float f; u32 u; } c; c.f = f;
  u32 u = c.u + 0x7fffu + ((c.u >> 16) & 1u);
  return (u16)(u >> 16);
}

__device__ __forceinline__ void gload_lds16(const void* g, void* l) {
  __builtin_amdgcn_global_load_lds(
      (const __attribute__((address_space(1))) u32*)g,
      (__attribute__((address_space(3))) u32*)l, 16, 0, 0);
}

// ---------------------------------------------------------------- conversion
__global__ void cvt_bf16_kernel(const float* __restrict__ s0, const float* __restrict__ s1,
                                const float* __restrict__ s2, const float* __restrict__ s3,
                                u16* __restrict__ d0, u16* __restrict__ d1,
                                u16* __restrict__ d2, u16* __restrict__ d3, int n4) {
  const int z = blockIdx.y;
  const float* s = (z == 0) ? s0 : (z == 1) ? s1 : (z == 2) ? s2 : s3;
  u16* d = (z == 0) ? d0 : (z == 1) ? d1 : (z == 2) ? d2 : d3;
  int i = blockIdx.x * blockDim.x + threadIdx.x;
  int stride = gridDim.x * blockDim.x;
  for (int k = i; k < n4; k += stride) {
    f4v v = ((const f4v*)s)[k];
    u16x4 o;
    o[0] = f2bf(v[0]); o[1] = f2bf(v[1]); o[2] = f2bf(v[2]); o[3] = f2bf(v[3]);
    ((u16x4*)d)[k] = o;
  }
}

// ---------------------------------------------------------------- GEMM  C = A * W^T (+bias)
// m97 structure: 128x128 tile, BK=64, 4 waves (2x2), single-buffer LDS (32KB),
// 2 barriers/K-step, global_load_lds width-16, XOR-swizzled frag reads (2-way=free).
// z = 0,1: C[M=4096][N=1024] = A X@W^T + col-bias.
// z = 2:   C[1024][4096] = Wv @ X^T + row-bias (transposed-output V projection);
//          tile decode swaps (x,y) so one dim3(32,8,3) launch covers all three.
template<int OUT_F32>
__global__ __launch_bounds__(256, 2) void gemm_bt_kernel(
    const u16* __restrict__ A0, const u16* __restrict__ A1, const u16* __restrict__ A2,
    const u16* __restrict__ W0, const u16* __restrict__ W1, const u16* __restrict__ W2,
    const float* __restrict__ b0, const float* __restrict__ b1, const float* __restrict__ b2,
    void* __restrict__ C0, void* __restrict__ C1, void* __restrict__ C2,
    int K) {
  const int z = blockIdx.z;
  const u16* A = (z == 0) ? A0 : (z == 1) ? A1 : A2;
  const u16* W = (z == 0) ? W0 : (z == 1) ? W1 : W2;
  const float* bias = (z == 0) ? b0 : (z == 1) ? b1 : b2;
  void* Cp = (z == 0) ? C0 : (z == 1) ? C1 : C2;
  const int bias_row = (z == 2);
  const int Nn = (z == 2) ? NT : DD;
  const int m0 = ((z == 2) ? blockIdx.y : blockIdx.x) * 128;
  const int n0 = ((z == 2) ? blockIdx.x : blockIdx.y) * 128;

  __shared__ u16 As[128 * 64];
  __shared__ u16 Bs[128 * 64];
  const int t = threadIdx.x;
  const int lane = t & 63, w = t >> 6;
  const int wr = w >> 1, wc = w & 1;
  const int l15 = lane & 15, l4 = lane >> 4;

  f32x4 acc[4][4];
#pragma unroll
  for (int m = 0; m < 4; ++m)
#pragma unroll
    for (int n = 0; n < 4; ++n) acc[m][n] = (f32x4)(0.0f);

  // pre-swizzled global sources (rule 21): LDS granule c holds global granule (c&7)^(row&7)
  const u16* aSrc[4];
  const u16* bSrc[4];
#pragma unroll
  for (int i = 0; i < 4; ++i) {
    int c = i * 256 + t, row = c >> 3, gg = (c & 7) ^ (row & 7);
    aSrc[i] = A + (size_t)(m0 + row) * K + gg * 8;
    bSrc[i] = W + (size_t)(n0 + row) * K + gg * 8;
  }

  const int nk = K >> 6;
  for (int kt = 0; kt < nk; ++kt) {
    __syncthreads();
#pragma unroll
    for (int i = 0; i < 4; ++i) {
      gload_lds16(aSrc[i] + kt * 64, &As[i * 2048 + w * 512]);
      gload_lds16(bSrc[i] + kt * 64, &Bs[i * 2048 + w * 512]);
    }
    __syncthreads();
    bf16x8 af[4][2], bfr[4][2];
#pragma unroll
    for (int m = 0; m < 4; ++m) {
      int row = wr * 64 + m * 16 + l15;
#pragma unroll
      for (int kf = 0; kf < 2; ++kf)
        af[m][kf] = *(const bf16x8*)&As[row * 64 + ((kf * 4 + l4) ^ (row & 7)) * 8];
    }
#pragma unroll
    for (int n = 0; n < 4; ++n) {
      int row = wc * 64 + n * 16 + l15;
#pragma unroll
      for (int kf = 0; kf < 2; ++kf)
        bfr[n][kf] = *(const bf16x8*)&Bs[row * 64 + ((kf * 4 + l4) ^ (row & 7)) * 8];
    }
#pragma unroll
    for (int kf = 0; kf < 2; ++kf)
#pragma unroll
      for (int m = 0; m < 4; ++m)
#pragma unroll
        for (int n = 0; n < 4; ++n)
          acc[m][n] = __builtin_amdgcn_mfma_f32_16x16x32_bf16(af[m][kf], bfr[n][kf], acc[m][n], 0, 0, 0);
  }

  float bvc[4];
#pragma unroll
  for (int n = 0; n < 4; ++n)
    bvc[n] = bias_row ? 0.0f : bias[n0 + wc * 64 + n * 16 + l15];
#pragma unroll
  for (int m = 0; m < 4; ++m) {
#pragma unroll
    for (int j = 0; j < 4; ++j) {
      int r = m0 + wr * 64 + m * 16 + l4 * 4 + j;
      float br = bias_row ? bias[r] : 0.0f;
#pragma unroll
      for (int n = 0; n < 4; ++n) {
        int cc = n0 + wc * 64 + n * 16 + l15;
        float v = acc[m][n][j] + (bias_row ? br : bvc[n]);
        if (OUT_F32) ((float*)Cp)[(size_t)r * Nn + cc] = v;
        else         ((u16*)Cp)[(size_t)r * Nn + cc] = f2bf(v);
      }
    }
  }
}

// ---------------------------------------------------------------- causal flash attention
// One wave per block, QBLK=32 rows, KBLK=64, zero barriers. 1D grid 2048 blocks:
// bh is the FASTEST dim so wgid%8 == bh%8 -> each XCD serves 4 heads (2MB K/V,
// L2-resident). LPT order (longest qt first) for scheduler packing. Register
// ping-pong K-prefetch; V from pre-transposed VtT; ones-column-MFMA row-sums;
// T13 defer-max (THR=8); s_setprio around MFMA clusters.
__global__ __launch_bounds__(64, 2) void attn_kernel(
    const u16* __restrict__ Qb, const u16* __restrict__ Kb,
    const u16* __restrict__ VtT, u16* __restrict__ Xb) {
  __shared__ u16 Pl[32 * 72];

  const int x = blockIdx.x;
  const int bh = x & 31;           // fastest -> XCD-pinned
  const int qt = 63 - (x >> 5);    // longest-first (LPT)
  const int b = bh >> 4, h = bh & 15;
  const int q0 = qt * 32;
  const int lane = threadIdx.x & 63;
  const int l15 = lane & 15, l4 = lane >> 4;

  // Q fragments: rows q0 + mf*16 + l15, dims kf*32 + l4*8
  bf16x8 aq[2][2];
#pragma unroll
  for (int mf = 0; mf < 2; ++mf)
#pragma unroll
    for (int kf = 0; kf < 2; ++kf)
      aq[mf][kf] = *(const bf16x8*)&Qb[((size_t)b * SS + q0 + mf * 16 + l15) * DD +
                                       h * 64 + kf * 32 + l4 * 8];

  const u16* Kbase = Kb + (size_t)b * SS * DD + h * 64;
  const u16* Vbase = VtT + (size_t)h * 64 * NT + (size_t)b * SS;

  // ones B-fragment: output col 0 = row-sum of P
  bf16x8 onesf;
#pragma unroll
  for (int e = 0; e < 8; ++e) onesf[e] = (l15 == 0) ? (short)0x3F80 : (short)0;

  f32x4 acc[2][4], accsum[2];
  float mrun[2][4];
#pragma unroll
  for (int mf = 0; mf < 2; ++mf) {
    accsum[mf] = (f32x4)(0.0f);
#pragma unroll
    for (int xk = 0; xk < 4; ++xk) { acc[mf][xk] = (f32x4)(0.0f); mrun[mf][xk] = -3.0e38f; }
  }

  auto loadK = [&](int kt, bf16x8 kfr[4][2]) {
    const int k0 = kt * 64;
#pragma unroll
    for (int nf = 0; nf < 4; ++nf) {
      const u16* kr = Kbase + (size_t)(k0 + nf * 16 + l15) * DD + l4 * 8;
      kfr[nf][0] = *(const bf16x8*)kr;
      kfr[nf][1] = *(const bf16x8*)(kr + 32);
    }
  };

  auto compute = [&](int kt, bf16x8 kfr[4][2]) {
    const int k0 = kt * 64;
    f32x4 s[2][4];
#pragma unroll
    for (int mf = 0; mf < 2; ++mf)
#pragma unroll
      for (int nf = 0; nf < 4; ++nf) s[mf][nf] = (f32x4)(0.0f);

    __builtin_amdgcn_s_setprio(1);
#pragma unroll
    for (int nf = 0; nf < 4; ++nf)
#pragma unroll
      for (int kf = 0; kf < 2; ++kf)
#pragma unroll
        for (int mf = 0; mf < 2; ++mf)
          s[mf][nf] = __builtin_amdgcn_mfma_f32_16x16x32_bf16(aq[mf][kf], kfr[nf][kf], s[mf][nf], 0, 0, 0);
    __builtin_amdgcn_s_setprio(0);

    // V fragments issued now — softmax below covers the latency
    bf16x8 vf[4][2];
#pragma unroll
    for (int nd = 0; nd < 4; ++nd) {
      const u16* vr = Vbase + (size_t)(nd * 16 + l15) * NT + k0 + l4 * 8;
      vf[nd][0] = *(const bf16x8*)vr;
      vf[nd][1] = *(const bf16x8*)(vr + 32);
    }

#pragma unroll
    for (int mf = 0; mf < 2; ++mf) {
      const bool need_mask = (k0 + 63 > q0 + mf * 16);
#pragma unroll
      for (int nf = 0; nf < 4; ++nf)
#pragma unroll
        for (int j = 0; j < 4; ++j) {
          float v = s[mf][nf][j] * ATT_SCALE;
          if (need_mask) {
            int key = k0 + nf * 16 + l15;
            int qrow = q0 + mf * 16 + l4 * 4 + j;
            if (key > qrow) v = -1.0e9f;
          }
          s[mf][nf][j] = v;
        }
    }

    // row max (shfl chain); sum handled by ones-MFMA
    float pmax[2][4];
#pragma unroll
    for (int mf = 0; mf < 2; ++mf)
#pragma unroll
      for (int j = 0; j < 4; ++j) {
        float v = fmaxf(fmaxf(s[mf][0][j], s[mf][1][j]), fmaxf(s[mf][2][j], s[mf][3][j]));
        v = fmaxf(v, __shfl_xor(v, 1));
        v = fmaxf(v, __shfl_xor(v, 2));
        v = fmaxf(v, __shfl_xor(v, 4));
        v = fmaxf(v, __shfl_xor(v, 8));
        pmax[mf][j] = v;
      }

    // T13 defer-max: rescale only when max grew by > 8
    int ok = 1;
#pragma unroll
    for (int mf = 0; mf < 2; ++mf)
#pragma unroll
      for (int j = 0; j < 4; ++j) ok &= (pmax[mf][j] - mrun[mf][j] <= 8.0f) ? 1 : 0;
    if (!__all(ok)) {
#pragma unroll
      for (int mf = 0; mf < 2; ++mf)
#pragma unroll
        for (int j = 0; j < 4; ++j) {
          float mnew = fmaxf(mrun[mf][j], pmax[mf][j]);
          float sc = __expf(mrun[mf][j] - mnew);
          mrun[mf][j] = mnew;
          accsum[mf][j] *= sc;
#pragma unroll
          for (int nd = 0; nd < 4; ++nd) acc[mf][nd][j] *= sc;
        }
    }

#pragma unroll
    for (int mf = 0; mf < 2; ++mf)
#pragma unroll
      for (int nf = 0; nf < 4; ++nf)
#pragma unroll
        for (int j = 0; j < 4; ++j)
          s[mf][nf][j] = __expf(s[mf][nf][j] - mrun[mf][j]);

    // P relayout through wave-local LDS (no barriers)
#pragma unroll
    for (int mf = 0; mf < 2; ++mf)
#pragma unroll
      for (int nf = 0; nf < 4; ++nf)
#pragma unroll
        for (int j = 0; j < 4; ++j)
          Pl[(mf * 16 + l4 * 4 + j) * 72 + nf * 16 + l15] = f2bf(s[mf][nf][j]);

    bf16x8 ap[2][2];
#pragma unroll
    for (int mf = 0; mf < 2; ++mf)
#pragma unroll
      for (int kf = 0; kf < 2; ++kf)
        ap[mf][kf] = *(const bf16x8*)&Pl[(mf * 16 + l15) * 72 + kf * 32 + l4 * 8];

    __builtin_amdgcn_s_setprio(1);
#pragma unroll
    for (int nd = 0; nd < 4; ++nd)
#pragma unroll
      for (int kf = 0; kf < 2; ++kf)
#pragma unroll
        for (int mf = 0; mf < 2; ++mf)
          acc[mf][nd] = __builtin_amdgcn_mfma_f32_16x16x32_bf16(ap[mf][kf], vf[nd][kf], acc[mf][nd], 0, 0, 0);
#pragma unroll
    for (int mf = 0; mf < 2; ++mf)
#pragma unroll
      for (int kf = 0; kf < 2; ++kf)
        accsum[mf] = __builtin_amdgcn_mfma_f32_16x16x32_bf16(ap[mf][kf], onesf, accsum[mf], 0, 0, 0);
    __builtin_amdgcn_s_setprio(0);
  };

  const int nkt = (qt >> 1) + 1;
  bf16x8 kA[4][2], kB[4][2];
  loadK(0, kA);
  for (int kt = 0; kt < nkt;) {
    if (kt + 1 < nkt) loadK(kt + 1, kB);  // prefetch off the critical path
    compute(kt, kA);
    ++kt;
    if (kt >= nkt) break;
    if (kt + 1 < nkt) loadK(kt + 1, kA);
    compute(kt, kB);
    ++kt;
  }

  // epilogue: row-sum lives in col-0 lanes of accsum; broadcast then write
#pragma unroll
  for (int mf = 0; mf < 2; ++mf)
#pragma unroll
    for (int j = 0; j < 4; ++j) {
      float lsum = __shfl(accsum[mf][j], l4 * 16);
      float inv = 1.0f / lsum;
      int srow = q0 + mf * 16 + l4 * 4 + j;
      size_t base = (size_t)b * SS * DD + (size_t)h * SS * 64 + (size_t)srow * 64;
#pragma unroll
      for (int nd = 0; nd < 4; ++nd)
        Xb[base + nd * 16 + l15] = f2bf(acc[mf][nd][j] * inv);
    }
}

// ---------------------------------------------------------------- launch
extern "C" void kernel_launch(void* const* d_in, const int* in_sizes, int n_in,
                              void* d_out, int out_size, void* d_ws, size_t ws_size,
                              hipStream_t stream) {
  const float* q_in = (const float*)d_in[0];
  const float* k_in = (const float*)d_in[1];
  const float* v_in = (const float*)d_in[2];
  const float* Wq = (const float*)d_in[3];
  const float* bq = (const float*)d_in[4];
  const float* Wk = (const float*)d_in[5];
  const float* bk = (const float*)d_in[6];
  const float* Wv = (const float*)d_in[7];
  const float* bv = (const float*)d_in[8];
  const float* Wo = (const float*)d_in[9];
  const float* bo = (const float*)d_in[10];

  char* ws = (char*)d_ws;
  const size_t SZ_IN = (size_t)BB * SS * DD * 2;  // 8 MiB bf16
  const size_t SZ_W = (size_t)DD * DD * 2;        // 2 MiB bf16
  u16* qb  = (u16*)(ws);
  u16* kb  = (u16*)(ws + SZ_IN);
  u16* vb  = (u16*)(ws + 2 * SZ_IN);
  u16* wqb = (u16*)(ws + 3 * SZ_IN);
  u16* wkb = (u16*)(ws + 3 * SZ_IN + SZ_W);
  u16* wvb = (u16*)(ws + 3 * SZ_IN + 2 * SZ_W);
  u16* wob = (u16*)(ws + 3 * SZ_IN + 3 * SZ_W);
  u16* Qb  = (u16*)(ws + 3 * SZ_IN + 4 * SZ_W);
  u16* Kb  = (u16*)(ws + 4 * SZ_IN + 4 * SZ_W);
  u16* VtT = (u16*)(ws + 5 * SZ_IN + 4 * SZ_W);  // [1024 dims][4096 tokens]
  u16* Xb  = (u16*)(ws + 6 * SZ_IN + 4 * SZ_W);

  // fp32 -> bf16
  cvt_bf16_kernel<<<dim3(2048, 3), 256, 0, stream>>>(q_in, k_in, v_in, nullptr,
                                                     qb, kb, vb, nullptr, (BB * SS * DD) / 4);
  cvt_bf16_kernel<<<dim3(1024, 4), 256, 0, stream>>>(Wq, Wk, Wv, Wo,
                                                     wqb, wkb, wvb, wob, (DD * DD) / 4);

  // all three projections in ONE launch (768 blocks = 3 blocks/CU):
  //   z=0: Q = X@Wq^T + bq      -> Qb  [4096][1024]
  //   z=1: K = X@Wk^T + bk      -> Kb  [4096][1024]
  //   z=2: V^T = Wv@X^T (+row)  -> VtT [1024][4096]
  gemm_bt_kernel<0><<<dim3(32, 8, 3), 256, 0, stream>>>(
      qb, kb, wvb, wqb, wkb, vb, bq, bk, bv, Qb, Kb, VtT, DD);

  // causal attention (XCD-pinned heads, LPT order, barrier-free)
  attn_kernel<<<dim3(64 * 32), 64, 0, stream>>>(Qb, Kb, VtT, Xb);

  // output projection (fp32 out)
  gemm_bt_kernel<1><<<dim3(32, 8, 1), 256, 0, stream>>>(
      Xb, nullptr, nullptr, wob, nullptr, nullptr, bo, nullptr, nullptr,
      d_out, nullptr, nullptr, DD);
}